// Round 1
// baseline (10476.336 us; speedup 1.0000x reference)
//
#include <hip/hip_runtime.h>
#include <math.h>

// Problem constants (B=2, S=512, D=2560, F=10240, H=32, DH=80, L=2)
#define BB 2
#define SS 512
#define DD 2560
#define FF 10240
#define HH 32
#define DHH 80
#define MR 1024   // B*S rows

// ---------------------------------------------------------------------------
// Embedding: x[row,:] = wte[ids[row],:] + wpe[row % S,:]
// ---------------------------------------------------------------------------
__global__ void embed_kernel(const int* __restrict__ ids,
                             const float* __restrict__ wte,
                             const float* __restrict__ wpe,
                             float* __restrict__ x) {
  int row = blockIdx.x;
  int id = ids[row];
  int pos = row % SS;
  const float4* tw = (const float4*)(wte + (size_t)id * DD);
  const float4* tp = (const float4*)(wpe + (size_t)pos * DD);
  float4* xo = (float4*)(x + (size_t)row * DD);
  for (int i = threadIdx.x; i < DD / 4; i += blockDim.x) {
    float4 a = tw[i], p = tp[i];
    xo[i] = make_float4(a.x + p.x, a.y + p.y, a.z + p.z, a.w + p.w);
  }
}

// ---------------------------------------------------------------------------
// LayerNorm (one block per row, 256 threads). h = (x-mean)*g*rsqrt(var+eps)+b
// ---------------------------------------------------------------------------
__global__ __launch_bounds__(256) void ln_kernel(const float* __restrict__ x,
                                                 const float* __restrict__ g,
                                                 const float* __restrict__ b,
                                                 float* __restrict__ out) {
  int row = blockIdx.x;
  int tid = threadIdx.x;
  const float2* xr = (const float2*)(x + (size_t)row * DD);
  float2 vals[5];
  float sum = 0.f, sq = 0.f;
#pragma unroll
  for (int i = 0; i < 5; ++i) {
    float2 v2 = xr[tid + i * 256];
    vals[i] = v2;
    sum += v2.x + v2.y;
    sq += v2.x * v2.x + v2.y * v2.y;
  }
  __shared__ float rs[8], rq[8];
#pragma unroll
  for (int o = 32; o > 0; o >>= 1) {
    sum += __shfl_down(sum, o);
    sq += __shfl_down(sq, o);
  }
  int wid = tid >> 6;
  if ((tid & 63) == 0) { rs[wid] = sum; rq[wid] = sq; }
  __syncthreads();
  if (tid == 0) {
    float s = rs[0] + rs[1] + rs[2] + rs[3];
    float s2 = rq[0] + rq[1] + rq[2] + rq[3];
    float mean = s / DD;
    float var = s2 / DD - mean * mean;
    rs[4] = mean;
    rq[4] = rsqrtf(var + 1e-12f);
  }
  __syncthreads();
  float mean = rs[4], inv = rq[4];
  float2* orow = (float2*)(out + (size_t)row * DD);
  const float2* gg = (const float2*)g;
  const float2* bb = (const float2*)b;
#pragma unroll
  for (int i = 0; i < 5; ++i) {
    int idx = tid + i * 256;
    float2 v2 = vals[i], g2 = gg[idx], b2 = bb[idx];
    float2 o;
    o.x = (v2.x - mean) * inv * g2.x + b2.x;
    o.y = (v2.y - mean) * inv * g2.y + b2.y;
    orow[idx] = o;
  }
}

// ---------------------------------------------------------------------------
// fp32 GEMM: C = A[M,K] @ W[K,N] + bias (+res) (gelu). 128x128x8 tile,
// 256 threads, 8x8 outputs/thread (strided 16-apart mapping: conflict-free).
// EPI: 0 = bias only, 1 = bias + residual add, 2 = bias + exact GELU
// ---------------------------------------------------------------------------
__device__ __forceinline__ float gelu_exact(float v) {
  return 0.5f * v * (1.f + erff(v * 0.70710678118654752f));
}

template <int EPI>
__global__ __launch_bounds__(256) void gemm_kernel(
    const float* __restrict__ A, const float* __restrict__ W,
    const float* __restrict__ bias, const float* __restrict__ res,
    float* __restrict__ C, int N, int K) {
  __shared__ float As[8][128];
  __shared__ float Ws[8][128];
  int tid = threadIdx.x;
  int m0 = blockIdx.y * 128, n0 = blockIdx.x * 128;
  int tx = tid & 15, ty = tid >> 4;

  float acc[8][8];
#pragma unroll
  for (int i = 0; i < 8; ++i)
#pragma unroll
    for (int j = 0; j < 8; ++j) acc[i][j] = 0.f;

  int arow = tid >> 1;          // 0..127
  int acol = (tid & 1) * 4;     // 0 or 4
  int wrow = tid >> 5;          // 0..7
  int wcol = (tid & 31) * 4;    // 0..124
  const float* Ag = A + (size_t)(m0 + arow) * K + acol;
  const float* Wg = W + (size_t)wrow * N + n0 + wcol;

  for (int k0 = 0; k0 < K; k0 += 8) {
    float4 av = *(const float4*)(Ag + k0);
    float4 wv = *(const float4*)(Wg + (size_t)k0 * N);
    __syncthreads();  // previous iteration's LDS reads complete
    As[acol + 0][arow] = av.x;
    As[acol + 1][arow] = av.y;
    As[acol + 2][arow] = av.z;
    As[acol + 3][arow] = av.w;
    *(float4*)&Ws[wrow][wcol] = wv;
    __syncthreads();
#pragma unroll
    for (int kk = 0; kk < 8; ++kk) {
      float a[8], w[8];
      *(float4*)&a[0] = *(const float4*)&As[kk][ty * 4];
      *(float4*)&a[4] = *(const float4*)&As[kk][ty * 4 + 64];
      *(float4*)&w[0] = *(const float4*)&Ws[kk][tx * 4];
      *(float4*)&w[4] = *(const float4*)&Ws[kk][tx * 4 + 64];
#pragma unroll
      for (int i = 0; i < 8; ++i)
#pragma unroll
        for (int j = 0; j < 8; ++j) acc[i][j] = fmaf(a[i], w[j], acc[i][j]);
    }
  }

#pragma unroll
  for (int i = 0; i < 8; ++i) {
    int gm = m0 + ty * 4 + (i & 3) + (i >> 2) * 64;
    float* crow = C + (size_t)gm * N + n0;
#pragma unroll
    for (int jh = 0; jh < 2; ++jh) {
      int gc = tx * 4 + jh * 64;
      float4 bv = *(const float4*)(bias + n0 + gc);
      float4 o;
      o.x = acc[i][jh * 4 + 0] + bv.x;
      o.y = acc[i][jh * 4 + 1] + bv.y;
      o.z = acc[i][jh * 4 + 2] + bv.z;
      o.w = acc[i][jh * 4 + 3] + bv.w;
      if constexpr (EPI == 1) {
        float4 r4 = *(const float4*)(res + (size_t)gm * N + n0 + gc);
        o.x += r4.x; o.y += r4.y; o.z += r4.z; o.w += r4.w;
      }
      if constexpr (EPI == 2) {
        o.x = gelu_exact(o.x); o.y = gelu_exact(o.y);
        o.z = gelu_exact(o.z); o.w = gelu_exact(o.w);
      }
      *(float4*)(crow + gc) = o;
    }
  }
}

// ---------------------------------------------------------------------------
// Attention: block = (q-tile of 16 rows, head, batch). Full 512-key scores in
// LDS, causal mask, wave-parallel softmax, PV accumulate.
// q,k,v layouts: [B*S, D] with head h at column h*80.
// ---------------------------------------------------------------------------
__global__ __launch_bounds__(256) void attn_kernel(
    const float* __restrict__ q, const float* __restrict__ k,
    const float* __restrict__ v, float* __restrict__ ctx) {
  __shared__ __align__(16) float qs[16][80];
  __shared__ __align__(16) float kvs[64][80];
  __shared__ float sc[16][512];
  int qt = blockIdx.x;   // 0..31
  int h = blockIdx.y;    // 0..31
  int b = blockIdx.z;    // 0..1
  int tid = threadIdx.x;
  int q0 = qt * 16;
  const size_t hoff = (size_t)h * DHH;
  const float scale = 0.11180339887498949f;  // 1/sqrt(80)

  for (int idx = tid; idx < 16 * 80; idx += 256) {
    int r = idx / 80, d = idx % 80;
    qs[r][d] = q[(size_t)(b * SS + q0 + r) * DD + hoff + d];
  }
  __syncthreads();

  // ---- scores = q @ k^T / sqrt(DH), causal mask ----
  for (int kt = 0; kt < 8; ++kt) {
    __syncthreads();
    for (int idx = tid; idx < 64 * 80; idx += 256) {
      int rr = idx / 80, d = idx % 80;
      kvs[rr][d] = k[(size_t)(b * SS + kt * 64 + rr) * DD + hoff + d];
    }
    __syncthreads();
    int r = tid & 15, kk0 = tid >> 4;
#pragma unroll
    for (int ji = 0; ji < 4; ++ji) {
      int kk = kk0 + ji * 16;
      const float4* qa = (const float4*)qs[r];
      const float4* ka = (const float4*)kvs[kk];
      float s = 0.f;
#pragma unroll
      for (int d4 = 0; d4 < 20; ++d4) {
        float4 qv = qa[d4], kv = ka[d4];
        s += qv.x * kv.x + qv.y * kv.y + qv.z * kv.z + qv.w * kv.w;
      }
      s *= scale;
      int kpos = kt * 64 + kk;
      if (kpos > q0 + r) s -= 1e12f;  // causal: matches reference exactly
      sc[r][kpos] = s;
    }
  }
  __syncthreads();

  // ---- softmax per row (wave per row-group) ----
  int lane = tid & 63, w = tid >> 6;
  for (int r = w; r < 16; r += 4) {
    float mx = -1e30f;
#pragma unroll
    for (int i = 0; i < 8; ++i) mx = fmaxf(mx, sc[r][lane + i * 64]);
#pragma unroll
    for (int o = 32; o > 0; o >>= 1) mx = fmaxf(mx, __shfl_xor(mx, o));
    float e[8];
    float sum = 0.f;
#pragma unroll
    for (int i = 0; i < 8; ++i) {
      e[i] = expf(sc[r][lane + i * 64] - mx);
      sum += e[i];
    }
#pragma unroll
    for (int o = 32; o > 0; o >>= 1) sum += __shfl_xor(sum, o);
    float inv = 1.f / sum;
#pragma unroll
    for (int i = 0; i < 8; ++i) sc[r][lane + i * 64] = e[i] * inv;
  }
  __syncthreads();

  // ---- ctx = probs @ V ----
  float acc[5] = {0.f, 0.f, 0.f, 0.f, 0.f};
  int rr_[5], dd_[5];
#pragma unroll
  for (int i = 0; i < 5; ++i) {
    int o = tid + i * 256;
    rr_[i] = o / 80;
    dd_[i] = o % 80;
  }
  for (int vt = 0; vt < 8; ++vt) {
    __syncthreads();
    for (int idx = tid; idx < 64 * 80; idx += 256) {
      int rr = idx / 80, d = idx % 80;
      kvs[rr][d] = v[(size_t)(b * SS + vt * 64 + rr) * DD + hoff + d];
    }
    __syncthreads();
#pragma unroll 8
    for (int kk = 0; kk < 64; ++kk) {
#pragma unroll
      for (int i = 0; i < 5; ++i)
        acc[i] = fmaf(sc[rr_[i]][vt * 64 + kk], kvs[kk][dd_[i]], acc[i]);
    }
  }
#pragma unroll
  for (int i = 0; i < 5; ++i)
    ctx[(size_t)(b * SS + q0 + rr_[i]) * DD + hoff + dd_[i]] = acc[i];
}

// ---------------------------------------------------------------------------
extern "C" void kernel_launch(void* const* d_in, const int* in_sizes, int n_in,
                              void* d_out, int out_size, void* d_ws,
                              size_t ws_size, hipStream_t stream) {
  (void)in_sizes; (void)n_in; (void)out_size; (void)ws_size;
  const int* ids = (const int*)d_in[0];
  const float* wte = (const float*)d_in[1];
  const float* wpe = (const float*)d_in[2];
  const float* ln0_g = (const float*)d_in[3];
  const float* ln0_b = (const float*)d_in[4];
  const float* wq = (const float*)d_in[5];
  const float* bq = (const float*)d_in[6];
  const float* wk = (const float*)d_in[7];
  const float* bk = (const float*)d_in[8];
  const float* wv = (const float*)d_in[9];
  const float* bv = (const float*)d_in[10];
  const float* wo = (const float*)d_in[11];
  const float* bo = (const float*)d_in[12];
  const float* ln1_g = (const float*)d_in[13];
  const float* ln1_b = (const float*)d_in[14];
  const float* w1 = (const float*)d_in[15];
  const float* b1 = (const float*)d_in[16];
  const float* w2 = (const float*)d_in[17];
  const float* b2 = (const float*)d_in[18];

  float* x = (float*)d_out;  // residual stream lives in d_out
  float* ws = (float*)d_ws;
  const size_t MD = (size_t)MR * DD;
  float* h = ws;             // [M,D]  (LN out; also reused as ctx)
  float* u = ws + MD;        // [M,F]  (MLP hidden; q/k/v alias it while dead)
  float* q = u;
  float* kbuf = u + MD;
  float* vbuf = u + 2 * MD;
  float* ctx = h;            // ctx written after h's qkv consumers finish

  embed_kernel<<<MR, 256, 0, stream>>>(ids, wte, wpe, x);

  for (int l = 0; l < 2; ++l) {
    const size_t WDD = (size_t)DD * DD, WDF = (size_t)DD * FF;
    dim3 gD(DD / 128, MR / 128);
    dim3 gF(FF / 128, MR / 128);

    ln_kernel<<<MR, 256, 0, stream>>>(x, ln0_g + l * DD, ln0_b + l * DD, h);
    gemm_kernel<0><<<gD, 256, 0, stream>>>(h, wq + l * WDD, bq + l * DD,
                                           nullptr, q, DD, DD);
    gemm_kernel<0><<<gD, 256, 0, stream>>>(h, wk + l * WDD, bk + l * DD,
                                           nullptr, kbuf, DD, DD);
    gemm_kernel<0><<<gD, 256, 0, stream>>>(h, wv + l * WDD, bv + l * DD,
                                           nullptr, vbuf, DD, DD);
    attn_kernel<<<dim3(SS / 16, HH, BB), 256, 0, stream>>>(q, kbuf, vbuf, ctx);
    gemm_kernel<1><<<gD, 256, 0, stream>>>(ctx, wo + l * WDD, bo + l * DD, x,
                                           x, DD, DD);
    ln_kernel<<<MR, 256, 0, stream>>>(x, ln1_g + l * DD, ln1_b + l * DD, h);
    gemm_kernel<2><<<gF, 256, 0, stream>>>(h, w1 + l * WDF, b1 + l * FF,
                                           nullptr, u, FF, DD);
    gemm_kernel<1><<<gD, 256, 0, stream>>>(u, w2 + l * WDF, b2 + l * DD, x, x,
                                           DD, FF);
  }
}